// Round 7
// baseline (42.738 us; speedup 1.0000x reference)
//
#include <hip/hip_runtime.h>
#include <hip/hip_cooperative_groups.h>
#include <math.h>

namespace cg = cooperative_groups;

#define EPS 1e-8f
#define D 128
#define K 5

// Single cooperative dispatch: 256 blocks x 256 threads, 16 lanes per row
// (16 rows/block). Block partial -> agent-scope store; grid.sync(); block 0
// reduces the 256 partials (fixed index order -> bit-stable) to out[0].
// Rationale: hand-rolled cross-block handoffs cost >=5us on this chip
// (R3/R4/R6); this tries the vendor-tuned grid barrier instead.
__global__ __launch_bounds__(256) void simloss_coop(
    const float* __restrict__ ue,      // [B, D]
    const float* __restrict__ se,      // [B, D]
    const float* __restrict__ tu,      // [NU, D]
    const float* __restrict__ ts,      // [NS, D]
    const int*   __restrict__ busers,  // [B]
    const int*   __restrict__ negidx,  // [B, K]
    float*       __restrict__ out,     // [1]
    float*       __restrict__ partials,// [gridDim.x]
    int B, float invB)
{
    const int bid = blockIdx.x;
    const int t   = threadIdx.x;
    const int tid = bid * 256 + t;
    const int row = tid >> 4;          // one row per 16 lanes
    const int r   = t & 15;

    float diff = 0.0f;                 // neg_mean - pos
    if (row < B) {
        const int uidx = busers[row];
        int nidx[K];
        #pragma unroll
        for (int k = 0; k < K; ++k) nidx[k] = negidx[row * K + k];

        const float4* A  = (const float4*)(ue + (size_t)row * D);
        const float4* Bv = (const float4*)(se + (size_t)row * D);
        const float4 a0 = A[r],  a1 = A[r + 16];
        const float4 b0 = Bv[r], b1 = Bv[r + 16];
        float dot = a0.x*b0.x + a0.y*b0.y + a0.z*b0.z + a0.w*b0.w
                  + a1.x*b1.x + a1.y*b1.y + a1.z*b1.z + a1.w*b1.w;
        float na  = a0.x*a0.x + a0.y*a0.y + a0.z*a0.z + a0.w*a0.w
                  + a1.x*a1.x + a1.y*a1.y + a1.z*a1.z + a1.w*a1.w;
        float nb  = b0.x*b0.x + b0.y*b0.y + b0.z*b0.z + b0.w*b0.w
                  + b1.x*b1.x + b1.y*b1.y + b1.z*b1.z + b1.w*b1.w;

        const float4* Cv = (const float4*)(tu + (size_t)uidx * D);
        const float4 c0 = Cv[r], c1 = Cv[r + 16];
        float nc = c0.x*c0.x + c0.y*c0.y + c0.z*c0.z + c0.w*c0.w
                 + c1.x*c1.x + c1.y*c1.y + c1.z*c1.z + c1.w*c1.w;

        float dk[K], nk[K];
        #pragma unroll
        for (int k = 0; k < K; ++k) {
            const float4* E = (const float4*)(ts + (size_t)nidx[k] * D);
            const float4 e0 = E[r], e1 = E[r + 16];
            dk[k] = c0.x*e0.x + c0.y*e0.y + c0.z*e0.z + c0.w*e0.w
                  + c1.x*e1.x + c1.y*e1.y + c1.z*e1.z + c1.w*e1.w;
            nk[k] = e0.x*e0.x + e0.y*e0.y + e0.z*e0.z + e0.w*e0.w
                  + e1.x*e1.x + e1.y*e1.y + e1.z*e1.z + e1.w*e1.w;
        }

        #pragma unroll
        for (int off = 8; off > 0; off >>= 1) {
            dot += __shfl_xor(dot, off);
            na  += __shfl_xor(na,  off);
            nb  += __shfl_xor(nb,  off);
            nc  += __shfl_xor(nc,  off);
            #pragma unroll
            for (int k = 0; k < K; ++k) {
                dk[k] += __shfl_xor(dk[k], off);
                nk[k] += __shfl_xor(nk[k], off);
            }
        }

        const float pos = dot * rsqrtf(fmaxf(na, EPS * EPS))
                              * rsqrtf(fmaxf(nb, EPS * EPS));
        const float rc  = rsqrtf(fmaxf(nc, EPS * EPS));
        float s = 0.0f;
        #pragma unroll
        for (int k = 0; k < K; ++k)
            s += dk[k] * rc * rsqrtf(fmaxf(nk[k], EPS * EPS));
        diff = s * (1.0f / K) - pos;
    }

    __shared__ float sp[16];
    if (r == 0) sp[t >> 4] = diff;
    __syncthreads();
    if (t == 0) {
        float bp = 0.0f;
        #pragma unroll
        for (int i = 0; i < 16; ++i) bp += sp[i];
        // agent-scope store: bypass L1 so another XCD's reader sees it
        __hip_atomic_store((unsigned*)&partials[bid],
                           __builtin_bit_cast(unsigned, bp),
                           __ATOMIC_RELAXED, __HIP_MEMORY_SCOPE_AGENT);
    }

    cg::this_grid().sync();

    if (bid != 0) return;
    const int nblk = (int)gridDim.x;
    float s = 0.0f;
    if (t < nblk) {
        const unsigned u = __hip_atomic_load((unsigned*)&partials[t],
                              __ATOMIC_RELAXED, __HIP_MEMORY_SCOPE_AGENT);
        s = __builtin_bit_cast(float, u);
    }
    #pragma unroll
    for (int off = 32; off > 0; off >>= 1) s += __shfl_xor(s, off);

    __shared__ float lw[4];
    const int lane = t & 63, wave = t >> 6;
    if (lane == 0) lw[wave] = s;
    __syncthreads();
    if (t == 0)
        out[0] = 1.0f + (lw[0] + lw[1] + lw[2] + lw[3]) * invB;
}

extern "C" void kernel_launch(void* const* d_in, const int* in_sizes, int n_in,
                              void* d_out, int out_size, void* d_ws, size_t ws_size,
                              hipStream_t stream) {
    const float* ue = (const float*)d_in[0];
    const float* se = (const float*)d_in[1];
    const float* tu = (const float*)d_in[2];
    const float* ts = (const float*)d_in[3];
    const int*   bu = (const int*)d_in[4];
    const int*   ni = (const int*)d_in[5];
    float* out = (float*)d_out;

    int B = in_sizes[0] / D;                     // 4096
    int nblk = (B * 16 + 255) / 256;             // 256 blocks, 16 rows each
    float* partials = (float*)d_ws;              // nblk floats
    float invB = 1.0f / (float)B;

    void* args[] = { &ue, &se, &tu, &ts, &bu, &ni, &out, &partials, &B, &invB };
    hipLaunchCooperativeKernel((const void*)simloss_coop,
                               dim3(nblk), dim3(256), args, 0, stream);
}

// Round 8
// 11.070 us; speedup vs baseline: 3.8608x; 3.8608x over previous
//
#include <hip/hip_runtime.h>
#include <math.h>

#define EPS 1e-8f
#define D 128
#define K 5

// BEST MEASURED STRUCTURE (R5: 11.19 us). Two plain dispatches.
// Rationale from R3/R4/R6/R7: every single-dispatch cross-block handoff
// (same-address atomics, spin-poll, tickets, cooperative grid.sync) costs
// +5..+31 us on MI355X vs two graph nodes. Kernel-1 instruction tuning is
// also exhausted (halving shuffle count twice: -1.5 us then 0).
//
// Kernel 1: 16 lanes per batch row (4 rows/wave), 16 rows per 256-thread
// block. Each lane holds two float4 slices (16 lanes x 32B = 512B = one
// D=128 row). Per-row pos-cosine + mean of K neg-cosines; 4-step butterfly
// over the 16-lane group. One float partial (neg-pos sum) per block.
__global__ __launch_bounds__(256) void simloss_partial(
    const float* __restrict__ ue,      // [B, D]
    const float* __restrict__ se,      // [B, D]
    const float* __restrict__ tu,      // [NU, D]
    const float* __restrict__ ts,      // [NS, D]
    const int*   __restrict__ busers,  // [B]
    const int*   __restrict__ negidx,  // [B, K]
    float* __restrict__ partials,      // [gridDim.x]
    int B)
{
    const int t   = threadIdx.x;
    const int tid = blockIdx.x * 256 + t;
    const int row = tid >> 4;          // one row per 16 lanes
    const int r   = t & 15;            // lane within row

    float diff = 0.0f;                 // neg_mean - pos
    if (row < B) {
        const int uidx = busers[row];
        int nidx[K];
        #pragma unroll
        for (int k = 0; k < K; ++k) nidx[k] = negidx[row * K + k];

        const float4* A  = (const float4*)(ue + (size_t)row * D);
        const float4* Bv = (const float4*)(se + (size_t)row * D);
        const float4 a0 = A[r],  a1 = A[r + 16];
        const float4 b0 = Bv[r], b1 = Bv[r + 16];
        float dot = a0.x*b0.x + a0.y*b0.y + a0.z*b0.z + a0.w*b0.w
                  + a1.x*b1.x + a1.y*b1.y + a1.z*b1.z + a1.w*b1.w;
        float na  = a0.x*a0.x + a0.y*a0.y + a0.z*a0.z + a0.w*a0.w
                  + a1.x*a1.x + a1.y*a1.y + a1.z*a1.z + a1.w*a1.w;
        float nb  = b0.x*b0.x + b0.y*b0.y + b0.z*b0.z + b0.w*b0.w
                  + b1.x*b1.x + b1.y*b1.y + b1.z*b1.z + b1.w*b1.w;

        const float4* Cv = (const float4*)(tu + (size_t)uidx * D);
        const float4 c0 = Cv[r], c1 = Cv[r + 16];
        float nc = c0.x*c0.x + c0.y*c0.y + c0.z*c0.z + c0.w*c0.w
                 + c1.x*c1.x + c1.y*c1.y + c1.z*c1.z + c1.w*c1.w;

        float dk[K], nk[K];
        #pragma unroll
        for (int k = 0; k < K; ++k) {
            const float4* E = (const float4*)(ts + (size_t)nidx[k] * D);
            const float4 e0 = E[r], e1 = E[r + 16];
            dk[k] = c0.x*e0.x + c0.y*e0.y + c0.z*e0.z + c0.w*e0.w
                  + c1.x*e1.x + c1.y*e1.y + c1.z*e1.z + c1.w*e1.w;
            nk[k] = e0.x*e0.x + e0.y*e0.y + e0.z*e0.z + e0.w*e0.w
                  + e1.x*e1.x + e1.y*e1.y + e1.z*e1.z + e1.w*e1.w;
        }

        // Butterfly within the 16-lane group.
        #pragma unroll
        for (int off = 8; off > 0; off >>= 1) {
            dot += __shfl_xor(dot, off);
            na  += __shfl_xor(na,  off);
            nb  += __shfl_xor(nb,  off);
            nc  += __shfl_xor(nc,  off);
            #pragma unroll
            for (int k = 0; k < K; ++k) {
                dk[k] += __shfl_xor(dk[k], off);
                nk[k] += __shfl_xor(nk[k], off);
            }
        }

        // norms ~ sqrt(128) >> eps; rsqrtf error ~1e-6 << 2e-2 threshold
        const float pos = dot * rsqrtf(fmaxf(na, EPS * EPS))
                              * rsqrtf(fmaxf(nb, EPS * EPS));
        const float rc  = rsqrtf(fmaxf(nc, EPS * EPS));
        float s = 0.0f;
        #pragma unroll
        for (int k = 0; k < K; ++k)
            s += dk[k] * rc * rsqrtf(fmaxf(nk[k], EPS * EPS));
        diff = s * (1.0f / K) - pos;
    }

    __shared__ float sp[16];
    if (r == 0) sp[t >> 4] = diff;
    __syncthreads();
    if (t == 0) {
        float bp = 0.0f;
        #pragma unroll
        for (int i = 0; i < 16; ++i) bp += sp[i];
        partials[blockIdx.x] = bp;
    }
}

// Kernel 2: ONE 64-lane wave. Each lane loads one float4 (256 partials),
// sums 4, 6-step butterfly, lane 0 writes the scalar. No LDS, no barrier.
__global__ __launch_bounds__(64) void simloss_final(
    const float* __restrict__ partials, float* __restrict__ out, float invB)
{
    const int t = threadIdx.x;
    const float4 v = ((const float4*)partials)[t];
    float s = v.x + v.y + v.z + v.w;
    #pragma unroll
    for (int off = 32; off > 0; off >>= 1) s += __shfl_xor(s, off);
    if (t == 0) out[0] = 1.0f + s * invB;
}

extern "C" void kernel_launch(void* const* d_in, const int* in_sizes, int n_in,
                              void* d_out, int out_size, void* d_ws, size_t ws_size,
                              hipStream_t stream) {
    const float* ue = (const float*)d_in[0];
    const float* se = (const float*)d_in[1];
    const float* tu = (const float*)d_in[2];
    const float* ts = (const float*)d_in[3];
    const int*   bu = (const int*)d_in[4];
    const int*   ni = (const int*)d_in[5];
    float* out = (float*)d_out;

    const int B = in_sizes[0] / D;               // 4096
    const int nblk = (B * 16 + 255) / 256;       // 256 blocks, 16 rows each
    float* partials = (float*)d_ws;              // 256 floats = 1 KB

    simloss_partial<<<nblk, 256, 0, stream>>>(ue, se, tu, ts, bu, ni, partials, B);
    simloss_final<<<1, 64, 0, stream>>>(partials, out, 1.0f / (float)B);
}